// Round 1
// baseline (1596.135 us; speedup 1.0000x reference)
//
#include <hip/hip_runtime.h>
#include <math.h>

// ---------------- problem constants ----------------
constexpr int B_   = 128;
constexpr int T_   = 512;
constexpr int MFEAT= 256;   // matrix feature dim
constexpr int CEMB = 64;    // core emb dim
constexpr int INL  = 320;   // MFEAT + CEMB
constexpr int H_   = 64;    // lstm hidden
constexpr int G4   = 256;   // 4*H
constexpr int GN_  = 8;     // gnn feature
constexpr int NG_  = 128;   // graphs
constexpr int NPG_ = 1024;  // nodes per graph
constexpr int NE_  = 2*1024*1024;
constexpr int M_   = B_*T_; // 65536 rows for pre-GEMM

// ---------------- workspace layout (bytes) ----------------
constexpr size_t OFF_PRE   = 0;                           // M_*G4 f32 = 64MB
constexpr size_t OFF_PACK  = OFF_PRE + (size_t)M_*G4*4;   // NE_ u32 = 8MB
constexpr size_t OFF_CNT   = OFF_PACK + (size_t)NE_*4;    // 128 u32
constexpr size_t OFF_START = OFF_CNT + 512;               // 128 u32
constexpr size_t OFF_CUR   = OFF_START + 512;             // 128 u32
constexpr size_t OFF_RNNX  = OFF_CUR + 512;               // 128*8 f32
constexpr size_t OFF_GOUT  = OFF_RNNX + 4096;             // 128*64 f32

__device__ __forceinline__ float sigf(float x){ return 1.f/(1.f+__expf(-x)); }
__device__ __forceinline__ float tanh_f(float x){
  float xc = fminf(fmaxf(x, -15.f), 15.f);
  float t = __expf(2.f*xc);
  return (t-1.f)/(t+1.f);
}

// ================= K1: pre-gate GEMM  pre[m][g] = x[m][:]@Wih0.T + b0 =================
// x = concat(matrix, core_emb[core_terms]) built on the fly. 128x128 tile, KT=8.
__global__ void gemm_pre(const float* __restrict__ mat, const int* __restrict__ ct,
                         const float* __restrict__ emb, const float* __restrict__ Wih,
                         const float* __restrict__ b0, float* __restrict__ pre)
{
  __shared__ __align__(16) float As[8][128];
  __shared__ __align__(16) float Bs[8][128];
  const int tid = threadIdx.x;
  const int m0 = blockIdx.y*128, n0 = blockIdx.x*128;
  const int tr = tid>>4, tc = tid&15;
  const int ar = tid>>1, akq = (tid&1)*4;
  const int bn = tid&127, bkq = (tid>>7)*4;
  float acc[8][8] = {};
  for (int k0 = 0; k0 < INL; k0 += 8){
    // stage A tile (rows m0..m0+127, k0..k0+7), transposed into As[k][m]
    const int ka = k0 + akq;
    const int row = m0 + ar;
    float4 av;
    if (ka < MFEAT) av = *(const float4*)(mat + (size_t)row*MFEAT + ka);
    else { int c = ct[row]; av = *(const float4*)(emb + (size_t)c*CEMB + (ka - MFEAT)); }
    As[akq+0][ar]=av.x; As[akq+1][ar]=av.y; As[akq+2][ar]=av.z; As[akq+3][ar]=av.w;
    float4 bv = *(const float4*)(Wih + (size_t)(n0+bn)*INL + k0 + bkq);
    Bs[bkq+0][bn]=bv.x; Bs[bkq+1][bn]=bv.y; Bs[bkq+2][bn]=bv.z; Bs[bkq+3][bn]=bv.w;
    __syncthreads();
    #pragma unroll
    for (int kk=0;kk<8;kk++){
      float a[8], bb[8];
      *(float4*)&a[0]  = *(const float4*)&As[kk][tr*8];
      *(float4*)&a[4]  = *(const float4*)&As[kk][tr*8+4];
      *(float4*)&bb[0] = *(const float4*)&Bs[kk][tc*8];
      *(float4*)&bb[4] = *(const float4*)&Bs[kk][tc*8+4];
      #pragma unroll
      for (int i=0;i<8;i++)
        #pragma unroll
        for (int jx=0;jx<8;jx++) acc[i][jx] += a[i]*bb[jx];
    }
    __syncthreads();
  }
  float bias[8];
  *(float4*)&bias[0] = *(const float4*)(b0 + n0 + tc*8);
  *(float4*)&bias[4] = *(const float4*)(b0 + n0 + tc*8 + 4);
  #pragma unroll
  for (int i=0;i<8;i++){
    float* dst = pre + (size_t)(m0 + tr*8 + i)*G4 + n0 + tc*8;
    float4 v0 = { acc[i][0]+bias[0], acc[i][1]+bias[1], acc[i][2]+bias[2], acc[i][3]+bias[3] };
    float4 v1 = { acc[i][4]+bias[4], acc[i][5]+bias[5], acc[i][6]+bias[6], acc[i][7]+bias[7] };
    *(float4*)dst = v0;
    *(float4*)(dst+4) = v1;
  }
}

// ================= K2: fused 2-layer LSTM recurrence, one block per batch row =================
// Recurrent weights in registers (row j per thread). Activations applied by the
// producing thread (wave-uniform act choice), so the update step is pure arithmetic.
__global__ __launch_bounds__(256) void lstm_k(
    const float* __restrict__ pre, const float* __restrict__ Whh0,
    const float* __restrict__ Wih1, const float* __restrict__ Whh1,
    const float* __restrict__ b1, const float* __restrict__ Wr,
    const float* __restrict__ br, const int* __restrict__ length,
    float* __restrict__ rnnx)
{
  const int j = threadIdx.x;
  const int b = blockIdx.x;
  __shared__ __align__(16) float h0s[H_];
  __shared__ __align__(16) float h1s[H_];
  __shared__ float gs[G4];
  __shared__ float lastv[H_];
  float w0[64], wa[64], wb[64];
  #pragma unroll
  for (int k=0;k<16;k++){
    *(float4*)&w0[k*4] = *(const float4*)(Whh0 + (size_t)j*H_ + k*4);
    *(float4*)&wa[k*4] = *(const float4*)(Wih1 + (size_t)j*H_ + k*4);
    *(float4*)&wb[k*4] = *(const float4*)(Whh1 + (size_t)j*H_ + k*4);
  }
  const float bias1 = b1[j];
  const int q = j>>6;              // 0:i 1:f 2:g 3:o (wave-uniform)
  float c0 = 0.f, c1 = 0.f;
  if (j < H_){ h0s[j]=0.f; h1s[j]=0.f; }
  const int len = length[b];
  const float* preb = pre + (size_t)b*T_*G4;
  float gcur = preb[j];
  __syncthreads();
  for (int t=0;t<T_;t++){
    float gnext = (t+1<T_) ? preb[(size_t)(t+1)*G4 + j] : 0.f;
    // layer0 gate j
    float a0=0,a1=0,a2=0,a3=0;
    #pragma unroll
    for (int kb=0;kb<16;kb++){
      float4 h = *(const float4*)&h0s[kb*4];
      a0 += h.x*w0[kb*4+0]; a1 += h.y*w0[kb*4+1]; a2 += h.z*w0[kb*4+2]; a3 += h.w*w0[kb*4+3];
    }
    float gv = gcur + ((a0+a1)+(a2+a3));
    gs[j] = (q==2) ? tanh_f(gv) : sigf(gv);   // pre-activated
    __syncthreads();
    if (j < H_){
      c0 = gs[j+64]*c0 + gs[j]*gs[j+128];
      h0s[j] = gs[j+192]*tanh_f(c0);
    }
    __syncthreads();
    // layer1 gate j
    float e0=0,e1=0,e2=0,e3=0;
    #pragma unroll
    for (int kb=0;kb<16;kb++){
      float4 h = *(const float4*)&h0s[kb*4];
      e0 += h.x*wa[kb*4+0]; e1 += h.y*wa[kb*4+1]; e2 += h.z*wa[kb*4+2]; e3 += h.w*wa[kb*4+3];
    }
    #pragma unroll
    for (int kb=0;kb<16;kb++){
      float4 h = *(const float4*)&h1s[kb*4];
      e0 += h.x*wb[kb*4+0]; e1 += h.y*wb[kb*4+1]; e2 += h.z*wb[kb*4+2]; e3 += h.w*wb[kb*4+3];
    }
    float g1 = bias1 + ((e0+e1)+(e2+e3));
    gs[j] = (q==2) ? tanh_f(g1) : sigf(g1);
    __syncthreads();
    if (j < H_){
      c1 = gs[j+64]*c1 + gs[j]*gs[j+128];
      float h1v = gs[j+192]*tanh_f(c1);
      h1s[j] = h1v;
      if (t == len-1) lastv[j] = h1v;
    }
    __syncthreads();
    gcur = gnext;
  }
  if (j < GN_){
    float s = br[j];
    #pragma unroll
    for (int k=0;k<H_;k++) s += lastv[k]*Wr[j*H_+k];
    rnnx[b*GN_+j] = s;
  }
}

// ================= K3: edge bucketing by graph =================
__global__ void edge_count(const int* __restrict__ src, unsigned* __restrict__ cnt)
{
  __shared__ unsigned lc[NG_];
  const int t = threadIdx.x;
  if (t < NG_) lc[t] = 0;
  __syncthreads();
  const int eb = blockIdx.x*2048;
  for (int i=t;i<2048;i+=256) atomicAdd(&lc[(unsigned)src[eb+i]>>10], 1u);
  __syncthreads();
  if (t < NG_ && lc[t]) atomicAdd(&cnt[t], lc[t]);
}

__global__ void edge_scan(const unsigned* __restrict__ cnt, unsigned* __restrict__ starts,
                          unsigned* __restrict__ cursor)
{
  if (threadIdx.x==0){
    unsigned s=0;
    for (int g2=0; g2<NG_; g2++){ starts[g2]=s; cursor[g2]=s; s+=cnt[g2]; }
  }
}

__global__ void edge_scatter(const int* __restrict__ src, const int* __restrict__ dst,
                             unsigned* __restrict__ cursor, unsigned* __restrict__ packed)
{
  __shared__ unsigned lc[NG_], base[NG_];
  const int t = threadIdx.x;
  if (t < NG_) lc[t] = 0;
  __syncthreads();
  const int eb = blockIdx.x*2048;
  for (int i=t;i<2048;i+=256) atomicAdd(&lc[(unsigned)src[eb+i]>>10], 1u);
  __syncthreads();
  if (t < NG_){
    unsigned c = lc[t];
    base[t] = c ? atomicAdd(&cursor[t], c) : 0u;
    lc[t] = 0;
  }
  __syncthreads();
  for (int i=t;i<2048;i+=256){
    unsigned s = (unsigned)src[eb+i], d = (unsigned)dst[eb+i];
    unsigned g2 = s>>10;
    unsigned off = atomicAdd(&lc[g2], 1u);
    packed[base[g2]+off] = (s & 1023u) | ((d & 1023u) << 10);
  }
}

// ================= K4: whole-GNN-in-LDS, one block (1024 threads) per graph =================
__global__ __launch_bounds__(1024) void gnn_k(
  const float* __restrict__ xg, const unsigned* __restrict__ packed,
  const unsigned* __restrict__ starts, const unsigned* __restrict__ cnt,
  const float* __restrict__ gcnW, const float* __restrict__ gcnB,
  const float* __restrict__ topkW, const float* __restrict__ gateW,
  const float* __restrict__ gateB, const float* __restrict__ attW,
  const float* __restrict__ attB, float* __restrict__ gout)
{
  extern __shared__ __align__(16) char smem[];
  float* xT    = (float*)smem;        // [8][1024] feature-major current features
  float* aT    = xT + 8*1024;         // [8][1024] aggregation buf; aliased as u64 keys[1024] during topk
  float* nmdi  = aT + 8*1024;         // [1024] nmask(0/1) outside GCN, dinv inside GCN
  float* aux   = nmdi + 1024;         // [1024] deg counts -> masked scores
  float* red   = aux + 1024;          // [160] cross-wave reduce
  float* outacc= red + 160;           // [64]
  float* pAttW = outacc + 64;         // [512]
  float* pAttB = pAttW + 512;         // [64]
  float* pW    = pAttB + 64;          // [64]
  float* pB    = pW + 64;             // [8]
  float* pT    = pB + 8;              // [8]
  float* pGW   = pT + 8;              // [8]
  float* pGB   = pGW + 8;             // [1]

  const int tid = threadIdx.x;
  const int g2  = blockIdx.x;
  const int i   = tid;                // owned node (local)
  {
    const float* xr = xg + (size_t)(g2*NPG_ + i)*GN_;
    float4 v0 = *(const float4*)(xr);
    float4 v1 = *(const float4*)(xr+4);
    xT[0*1024+i]=v0.x; xT[1*1024+i]=v0.y; xT[2*1024+i]=v0.z; xT[3*1024+i]=v0.w;
    xT[4*1024+i]=v1.x; xT[5*1024+i]=v1.y; xT[6*1024+i]=v1.z; xT[7*1024+i]=v1.w;
    nmdi[i] = 1.f;
  }
  if (tid < 512) pAttW[tid] = attW[tid];
  if (tid < 64) { pAttB[tid] = attB[tid]; outacc[tid] = 0.f; }
  const unsigned estart = starts[g2], ecnt = cnt[g2];
  float nactf = 1024.f;

  for (int it=0; it<4; ++it){
    if (tid < 64) pW[tid] = gcnW[it*64+tid];
    if (tid < 8) { pB[tid] = gcnB[it*8+tid]; pT[tid] = topkW[it*8+tid]; pGW[tid] = gateW[tid]; }
    if (tid == 0) pGB[0] = gateB[0];
    aux[i] = 0.f;
    __syncthreads();
    // ---- deg: aux[d] = sum over edges of nmask[src] (nmdi holds nmask 0/1 here)
    for (unsigned e=tid; e<ecnt; e+=1024){
      unsigned p = packed[estart+e];
      int s = p & 1023, d = (p>>10) & 1023;
      if (nmdi[s] != 0.f) atomicAdd(&aux[d], 1.f);
    }
    __syncthreads();
    // ---- dinv (nmdi becomes dinv); zero agg buffer
    {
      float nmv = nmdi[i];
      nmdi[i] = (nmv != 0.f) ? (1.f/sqrtf(1.f + aux[i])) : 0.f;
      #pragma unroll
      for (int f=0;f<8;f++) aT[f*1024+i] = 0.f;
    }
    __syncthreads();
    // ---- aggregate raw x over edges with coef = dinv[s]*dinv[d]
    for (unsigned e=tid; e<ecnt; e+=1024){
      unsigned p = packed[estart+e];
      int s = p & 1023, d = (p>>10) & 1023;
      float co = nmdi[s]*nmdi[d];
      if (co != 0.f){
        #pragma unroll
        for (int f=0;f<8;f++) atomicAdd(&aT[f*1024+d], xT[f*1024+s]*co);
      }
    }
    __syncthreads();
    // ---- node transform: x = relu((W(agg + dinv^2 * x) + b) * nm)
    {
      float di = nmdi[i], d2 = di*di;
      float msk = (di != 0.f) ? 1.f : 0.f;
      float u[8];
      #pragma unroll
      for (int f=0;f<8;f++) u[f] = aT[f*1024+i] + d2*xT[f*1024+i];
      #pragma unroll
      for (int f=0;f<8;f++){
        float v = pB[f];
        #pragma unroll
        for (int fp=0;fp<8;fp++) v += pW[f*8+fp]*u[fp];
        v *= msk;
        xT[f*1024+i] = v > 0.f ? v : 0.f;
      }
    }
    __syncthreads();
    // ---- topk: score, order-preserving u64 key (score desc, index asc)
    unsigned long long mykey;
    float myms;
    {
      float nrm = 0.f;
      #pragma unroll
      for (int f=0;f<8;f++) nrm += pT[f]*pT[f];
      float inv = 1.f/sqrtf(nrm);
      float s = 0.f;
      #pragma unroll
      for (int f=0;f<8;f++) s += xT[f*1024+i]*pT[f];
      s *= inv;
      s += 0.f;                                   // canonicalize -0 -> +0
      bool act = (nmdi[i] != 0.f);
      myms = act ? s : -INFINITY;
      aux[i] = myms;
      unsigned ub = __float_as_uint(myms);
      ub = (ub & 0x80000000u) ? ~ub : (ub | 0x80000000u);
      mykey = ((unsigned long long)ub << 32) | (unsigned)(~i);
      ((unsigned long long*)aT)[i] = mykey;
    }
    __syncthreads();
    int rank = 0;
    {
      const ulonglong2* kp = (const ulonglong2*)aT;
      for (int jb=0; jb<512; jb++){
        ulonglong2 kk = kp[jb];
        rank += (kk.x > mykey);
        rank += (kk.y > mykey);
      }
    }
    float kf = ceilf(0.8f*nactf);
    nactf = kf;
    const int kkeep = (int)kf;
    const bool keep = (rank < kkeep) && (nmdi[i] != 0.f);
    {
      float th = keep ? tanh_f(myms) : 0.f;
      #pragma unroll
      for (int f=0;f<8;f++) xT[f*1024+i] *= th;
      nmdi[i] = keep ? 1.f : 0.f;
    }
    __syncthreads();
    // ---- attpool: out += attW @ (softmax-weighted mean of x) + attB
    {
      float gi = pGB[0];
      #pragma unroll
      for (int f=0;f<8;f++) gi += xT[f*1024+i]*pGW[f];
      float gm = (nmdi[i] != 0.f) ? gi : -1e30f;
      float wm = gm;
      #pragma unroll
      for (int o=32;o>0;o>>=1) wm = fmaxf(wm, __shfl_xor(wm, o));
      const int wid = tid>>6;
      if ((tid&63)==0) red[wid] = wm;
      __syncthreads();
      float m = red[0];
      #pragma unroll
      for (int w=1;w<16;w++) m = fmaxf(m, red[w]);
      __syncthreads();
      float e = (nmdi[i] != 0.f) ? __expf(gi - m) : 0.f;
      float part[9];
      part[0] = e;
      #pragma unroll
      for (int f=0;f<8;f++) part[1+f] = e*xT[f*1024+i];
      #pragma unroll
      for (int qq=0;qq<9;qq++){
        float v = part[qq];
        #pragma unroll
        for (int o=32;o>0;o>>=1) v += __shfl_xor(v, o);
        if ((tid&63)==0) red[wid*9+qq] = v;
      }
      __syncthreads();
      if (tid < 64){
        float tot[9];
        #pragma unroll
        for (int qq=0;qq<9;qq++){
          float sv = 0.f;
          #pragma unroll
          for (int w=0;w<16;w++) sv += red[w*9+qq];
          tot[qq] = sv;
        }
        float sden = fmaxf(tot[0], 1e-12f);
        float o = pAttB[tid];
        #pragma unroll
        for (int f=0;f<8;f++) o += pAttW[tid*8+f]*(tot[1+f]/sden);
        outacc[tid] += o;
      }
      __syncthreads();
    }
  }
  if (tid < 64) gout[g2*64+tid] = outacc[tid];
}

// ================= K5: final combine =================
__global__ void combine_k(const float* __restrict__ rnnx, const float* __restrict__ gout,
                          const float* __restrict__ fcW, const float* __restrict__ fcb,
                          float* __restrict__ out)
{
  int b = threadIdx.x;
  if (b < B_){
    float s = fcb[0];
    #pragma unroll
    for (int q=0;q<8;q++) s += fcW[q]*rnnx[b*8+q];
    #pragma unroll
    for (int q=0;q<64;q++) s += fcW[8+q]*gout[b*64+q];
    out[b] = s;
  }
}

// ================= launch =================
extern "C" void kernel_launch(void* const* d_in, const int* in_sizes, int n_in,
                              void* d_out, int out_size, void* d_ws, size_t ws_size,
                              hipStream_t stream)
{
  const float* matrix    = (const float*)d_in[0];
  const int*   core_terms= (const int*)d_in[1];
  const int*   length    = (const int*)d_in[2];
  const float* x_graph   = (const float*)d_in[3];
  const int*   edge_src  = (const int*)d_in[4];
  const int*   edge_dst  = (const int*)d_in[5];
  // d_in[6] = batch (derivable, unused)
  const float* core_emb  = (const float*)d_in[7];
  const float* Wih0      = (const float*)d_in[8];
  const float* Whh0      = (const float*)d_in[9];
  const float* b0        = (const float*)d_in[10];
  const float* Wih1      = (const float*)d_in[11];
  const float* Whh1      = (const float*)d_in[12];
  const float* b1        = (const float*)d_in[13];
  const float* Wr        = (const float*)d_in[14];
  const float* br        = (const float*)d_in[15];
  const float* gcn_W     = (const float*)d_in[16];
  const float* gcn_b     = (const float*)d_in[17];
  const float* topk_w    = (const float*)d_in[18];
  const float* gate_W    = (const float*)d_in[19];
  const float* gate_b    = (const float*)d_in[20];
  const float* att_W     = (const float*)d_in[21];
  const float* att_b     = (const float*)d_in[22];
  const float* fc_W      = (const float*)d_in[23];
  const float* fc_b      = (const float*)d_in[24];
  float* out = (float*)d_out;

  char* ws = (char*)d_ws;
  float*    pre    = (float*)(ws + OFF_PRE);
  unsigned* packed = (unsigned*)(ws + OFF_PACK);
  unsigned* cnt    = (unsigned*)(ws + OFF_CNT);
  unsigned* starts = (unsigned*)(ws + OFF_START);
  unsigned* cursor = (unsigned*)(ws + OFF_CUR);
  float*    rnnx   = (float*)(ws + OFF_RNNX);
  float*    gout   = (float*)(ws + OFF_GOUT);

  hipMemsetAsync(cnt, 0, 512, stream);

  // edge bucketing
  edge_count  <<<NE_/2048, 256, 0, stream>>>(edge_src, cnt);
  edge_scan   <<<1, 64, 0, stream>>>(cnt, starts, cursor);
  edge_scatter<<<NE_/2048, 256, 0, stream>>>(edge_src, edge_dst, cursor, packed);

  // RNN path
  gemm_pre<<<dim3(2, M_/128), 256, 0, stream>>>(matrix, core_terms, core_emb, Wih0, b0, pre);
  lstm_k  <<<B_, 256, 0, stream>>>(pre, Whh0, Wih1, Whh1, b1, Wr, br, length, rnnx);

  // GNN path
  constexpr int GNN_SMEM = 19321*4;  // 77284 B, rounded where carved
  static int attr_set = -1;
  (void)attr_set;
  hipFuncSetAttribute((const void*)gnn_k, hipFuncAttributeMaxDynamicSharedMemorySize, GNN_SMEM);
  gnn_k<<<NG_, 1024, GNN_SMEM, stream>>>(x_graph, packed, starts, cnt, gcn_W, gcn_b,
                                         topk_w, gate_W, gate_b, att_W, att_b, gout);

  combine_k<<<1, 128, 0, stream>>>(rnnx, gout, fc_W, fc_b, out);
}

// Round 2
// 1576.618 us; speedup vs baseline: 1.0124x; 1.0124x over previous
//
#include <hip/hip_runtime.h>
#include <math.h>

// ---------------- problem constants ----------------
constexpr int B_   = 128;
constexpr int T_   = 512;
constexpr int MFEAT= 256;   // matrix feature dim
constexpr int CEMB = 64;    // core emb dim
constexpr int INL  = 320;   // MFEAT + CEMB
constexpr int H_   = 64;    // lstm hidden
constexpr int G4   = 256;   // 4*H
constexpr int GN_  = 8;     // gnn feature
constexpr int NG_  = 128;   // graphs
constexpr int NPG_ = 1024;  // nodes per graph
constexpr int NE_  = 2*1024*1024;
constexpr int M_   = B_*T_; // 65536 rows for pre-GEMM

// ---------------- workspace layout (bytes) ----------------
constexpr size_t OFF_PRE   = 0;                           // M_*G4 f32 = 64MB
constexpr size_t OFF_PACK  = OFF_PRE + (size_t)M_*G4*4;   // NE_ u32 = 8MB
constexpr size_t OFF_CNT   = OFF_PACK + (size_t)NE_*4;    // 128 u32
constexpr size_t OFF_START = OFF_CNT + 512;               // 128 u32
constexpr size_t OFF_CUR   = OFF_START + 512;             // 128 u32
constexpr size_t OFF_RNNX  = OFF_CUR + 512;               // 128*8 f32
constexpr size_t OFF_GOUT  = OFF_RNNX + 4096;             // 128*64 f32

__device__ __forceinline__ float sigf(float x){ return 1.f/(1.f+__expf(-x)); }
__device__ __forceinline__ float tanh_f(float x){
  float xc = fminf(fmaxf(x, -15.f), 15.f);
  float t = __expf(2.f*xc);
  return (t-1.f)/(t+1.f);
}
__device__ __forceinline__ float rlane(float v, int k){
  return __int_as_float(__builtin_amdgcn_readlane(__float_as_int(v), k));
}

// ================= K1: pre-gate GEMM  pre[m][g] = x[m][:]@Wih0.T + b0 =================
__global__ void gemm_pre(const float* __restrict__ mat, const int* __restrict__ ct,
                         const float* __restrict__ emb, const float* __restrict__ Wih,
                         const float* __restrict__ b0, float* __restrict__ pre)
{
  __shared__ __align__(16) float As[8][128];
  __shared__ __align__(16) float Bs[8][128];
  const int tid = threadIdx.x;
  const int m0 = blockIdx.y*128, n0 = blockIdx.x*128;
  const int tr = tid>>4, tc = tid&15;
  const int ar = tid>>1, akq = (tid&1)*4;
  const int bn = tid&127, bkq = (tid>>7)*4;
  float acc[8][8] = {};
  for (int k0 = 0; k0 < INL; k0 += 8){
    const int ka = k0 + akq;
    const int row = m0 + ar;
    float4 av;
    if (ka < MFEAT) av = *(const float4*)(mat + (size_t)row*MFEAT + ka);
    else { int c = ct[row]; av = *(const float4*)(emb + (size_t)c*CEMB + (ka - MFEAT)); }
    As[akq+0][ar]=av.x; As[akq+1][ar]=av.y; As[akq+2][ar]=av.z; As[akq+3][ar]=av.w;
    float4 bv = *(const float4*)(Wih + (size_t)(n0+bn)*INL + k0 + bkq);
    Bs[bkq+0][bn]=bv.x; Bs[bkq+1][bn]=bv.y; Bs[bkq+2][bn]=bv.z; Bs[bkq+3][bn]=bv.w;
    __syncthreads();
    #pragma unroll
    for (int kk=0;kk<8;kk++){
      float a[8], bb[8];
      *(float4*)&a[0]  = *(const float4*)&As[kk][tr*8];
      *(float4*)&a[4]  = *(const float4*)&As[kk][tr*8+4];
      *(float4*)&bb[0] = *(const float4*)&Bs[kk][tc*8];
      *(float4*)&bb[4] = *(const float4*)&Bs[kk][tc*8+4];
      #pragma unroll
      for (int i=0;i<8;i++)
        #pragma unroll
        for (int jx=0;jx<8;jx++) acc[i][jx] += a[i]*bb[jx];
    }
    __syncthreads();
  }
  float bias[8];
  *(float4*)&bias[0] = *(const float4*)(b0 + n0 + tc*8);
  *(float4*)&bias[4] = *(const float4*)(b0 + n0 + tc*8 + 4);
  #pragma unroll
  for (int i=0;i<8;i++){
    float* dst = pre + (size_t)(m0 + tr*8 + i)*G4 + n0 + tc*8;
    float4 v0 = { acc[i][0]+bias[0], acc[i][1]+bias[1], acc[i][2]+bias[2], acc[i][3]+bias[3] };
    float4 v1 = { acc[i][4]+bias[4], acc[i][5]+bias[5], acc[i][6]+bias[6], acc[i][7]+bias[7] };
    *(float4*)dst = v0;
    *(float4*)(dst+4) = v1;
  }
}

// ================= K2: pipelined 2-layer LSTM, 512 thr, 1 barrier/step =================
// Waves 0-3: layer0 gates(t).  Waves 4-7: layer1 gates(t-1).
// h0/h1/c0/c1 live lane-distributed in registers, redundantly updated per wave.
// Matvec broadcast via v_readlane (no LDS round trip for h).
__global__ __launch_bounds__(512) void lstm_k(
    const float* __restrict__ pre, const float* __restrict__ Whh0,
    const float* __restrict__ Wih1, const float* __restrict__ Whh1,
    const float* __restrict__ b1, const float* __restrict__ Wr,
    const float* __restrict__ br, const int* __restrict__ length,
    float* __restrict__ rnnx)
{
  const int tid  = threadIdx.x;
  const int b    = blockIdx.x;
  const int wav  = tid >> 6;       // 0..7
  const int lane = tid & 63;
  const bool isB = wav >= 4;
  const int q    = isB ? (wav - 4) : wav;   // gate group: 0:i 1:f 2:g 3:o
  const int row  = q*64 + lane;             // row in [0,256)

  __shared__ float gsb[2][2][G4];   // [parity][layer][gate*64+unit], pre-activated
  __shared__ float lastv[H_];

  float wa[64], wb[64];
  if (!isB){
    #pragma unroll
    for (int k=0;k<16;k++)
      *(float4*)&wa[k*4] = *(const float4*)(Whh0 + (size_t)row*H_ + k*4);
  } else {
    #pragma unroll
    for (int k=0;k<16;k++){
      *(float4*)&wa[k*4] = *(const float4*)(Wih1 + (size_t)row*H_ + k*4);
      *(float4*)&wb[k*4] = *(const float4*)(Whh1 + (size_t)row*H_ + k*4);
    }
  }
  const float biasj = isB ? b1[row] : 0.f;

  float vh0 = 0.f, vh1 = 0.f, c0 = 0.f, c1 = 0.f, vlast = 0.f;
  const int len = length[b];
  const float* preb = pre + (size_t)b*T_*G4;
  float gcur = (!isB) ? preb[row] : 0.f;

  for (int t = 0; t <= T_; ++t){
    const int p = t & 1;
    if (!isB){
      if (t < T_){
        float gnext = (t+1 < T_) ? preb[(size_t)(t+1)*G4 + row] : 0.f;
        float a0 = gcur, a1 = 0.f, a2 = 0.f, a3 = 0.f;
        #pragma unroll
        for (int k=0;k<64;k+=4){
          a0 += rlane(vh0,k+0)*wa[k+0];
          a1 += rlane(vh0,k+1)*wa[k+1];
          a2 += rlane(vh0,k+2)*wa[k+2];
          a3 += rlane(vh0,k+3)*wa[k+3];
        }
        float g = (a0+a1)+(a2+a3);
        gsb[p][0][row] = (q==2) ? tanh_f(g) : sigf(g);
        gcur = gnext;
      }
    } else {
      if (t >= 1){
        float a0 = biasj, a1 = 0.f, a2 = 0.f, a3 = 0.f;
        #pragma unroll
        for (int k=0;k<64;k+=4){
          a0 += rlane(vh0,k+0)*wa[k+0];
          a1 += rlane(vh0,k+1)*wa[k+1];
          a2 += rlane(vh0,k+2)*wa[k+2];
          a3 += rlane(vh0,k+3)*wa[k+3];
        }
        #pragma unroll
        for (int k=0;k<64;k+=4){
          a0 += rlane(vh1,k+0)*wb[k+0];
          a1 += rlane(vh1,k+1)*wb[k+1];
          a2 += rlane(vh1,k+2)*wb[k+2];
          a3 += rlane(vh1,k+3)*wb[k+3];
        }
        float g = (a0+a1)+(a2+a3);
        gsb[p][1][row] = (q==2) ? tanh_f(g) : sigf(g);
      }
    }
    __syncthreads();
    // redundant per-wave cell updates (reads pre-activated gates)
    if (t < T_){
      float gi = gsb[p][0][lane];
      float gf = gsb[p][0][64+lane];
      float gg = gsb[p][0][128+lane];
      float go = gsb[p][0][192+lane];
      c0  = gf*c0 + gi*gg;
      vh0 = go*tanh_f(c0);
    }
    if (isB && t >= 1){
      float gi = gsb[p][1][lane];
      float gf = gsb[p][1][64+lane];
      float gg = gsb[p][1][128+lane];
      float go = gsb[p][1][192+lane];
      c1  = gf*c1 + gi*gg;
      vh1 = go*tanh_f(c1);
      if (t == len) vlast = vh1;   // vh1 == h1(len-1)
    }
  }
  if (wav == 4) lastv[lane] = vlast;
  __syncthreads();
  if (tid < GN_){
    float s = br[tid];
    #pragma unroll
    for (int k=0;k<H_;k++) s += lastv[k]*Wr[tid*H_+k];
    rnnx[b*GN_+tid] = s;
  }
}

// ================= K3: edge bucketing by graph =================
__global__ void edge_count(const int* __restrict__ src, unsigned* __restrict__ cnt)
{
  __shared__ unsigned lc[NG_];
  const int t = threadIdx.x;
  if (t < NG_) lc[t] = 0;
  __syncthreads();
  const int eb = blockIdx.x*2048;
  for (int i=t;i<2048;i+=256) atomicAdd(&lc[(unsigned)src[eb+i]>>10], 1u);
  __syncthreads();
  if (t < NG_ && lc[t]) atomicAdd(&cnt[t], lc[t]);
}

__global__ void edge_scan(const unsigned* __restrict__ cnt, unsigned* __restrict__ starts,
                          unsigned* __restrict__ cursor)
{
  if (threadIdx.x==0){
    unsigned s=0;
    for (int g2=0; g2<NG_; g2++){ starts[g2]=s; cursor[g2]=s; s+=cnt[g2]; }
  }
}

__global__ void edge_scatter(const int* __restrict__ src, const int* __restrict__ dst,
                             unsigned* __restrict__ cursor, unsigned* __restrict__ packed)
{
  __shared__ unsigned lc[NG_], base[NG_];
  const int t = threadIdx.x;
  if (t < NG_) lc[t] = 0;
  __syncthreads();
  const int eb = blockIdx.x*2048;
  for (int i=t;i<2048;i+=256) atomicAdd(&lc[(unsigned)src[eb+i]>>10], 1u);
  __syncthreads();
  if (t < NG_){
    unsigned c = lc[t];
    base[t] = c ? atomicAdd(&cursor[t], c) : 0u;
    lc[t] = 0;
  }
  __syncthreads();
  for (int i=t;i<2048;i+=256){
    unsigned s = (unsigned)src[eb+i], d = (unsigned)dst[eb+i];
    unsigned g2 = s>>10;
    unsigned off = atomicAdd(&lc[g2], 1u);
    packed[base[g2]+off] = (s & 1023u) | ((d & 1023u) << 10);
  }
}

// ================= K4: whole-GNN-in-LDS, one block (1024 threads) per graph =================
__global__ __launch_bounds__(1024) void gnn_k(
  const float* __restrict__ xg, const unsigned* __restrict__ packed,
  const unsigned* __restrict__ starts, const unsigned* __restrict__ cnt,
  const float* __restrict__ gcnW, const float* __restrict__ gcnB,
  const float* __restrict__ topkW, const float* __restrict__ gateW,
  const float* __restrict__ gateB, const float* __restrict__ attW,
  const float* __restrict__ attB, float* __restrict__ gout)
{
  extern __shared__ __align__(16) char smem[];
  float* xT    = (float*)smem;        // [8][1024]
  float* aT    = xT + 8*1024;         // [8][1024]; aliased u64 keys[1024] in topk
  float* nmdi  = aT + 8*1024;         // [1024]
  float* aux   = nmdi + 1024;         // [1024]
  float* red   = aux + 1024;          // [160]
  float* outacc= red + 160;           // [64]
  float* pAttW = outacc + 64;         // [512]
  float* pAttB = pAttW + 512;         // [64]
  float* pW    = pAttB + 64;          // [64]
  float* pB    = pW + 64;             // [8]
  float* pT    = pB + 8;              // [8]
  float* pGW   = pT + 8;              // [8]
  float* pGB   = pGW + 8;             // [1]

  const int tid = threadIdx.x;
  const int g2  = blockIdx.x;
  const int i   = tid;
  {
    const float* xr = xg + (size_t)(g2*NPG_ + i)*GN_;
    float4 v0 = *(const float4*)(xr);
    float4 v1 = *(const float4*)(xr+4);
    xT[0*1024+i]=v0.x; xT[1*1024+i]=v0.y; xT[2*1024+i]=v0.z; xT[3*1024+i]=v0.w;
    xT[4*1024+i]=v1.x; xT[5*1024+i]=v1.y; xT[6*1024+i]=v1.z; xT[7*1024+i]=v1.w;
    nmdi[i] = 1.f;
  }
  if (tid < 512) pAttW[tid] = attW[tid];
  if (tid < 64) { pAttB[tid] = attB[tid]; outacc[tid] = 0.f; }
  const unsigned estart = starts[g2], ecnt = cnt[g2];
  float nactf = 1024.f;

  for (int it=0; it<4; ++it){
    if (tid < 64) pW[tid] = gcnW[it*64+tid];
    if (tid < 8) { pB[tid] = gcnB[it*8+tid]; pT[tid] = topkW[it*8+tid]; pGW[tid] = gateW[tid]; }
    if (tid == 0) pGB[0] = gateB[0];
    aux[i] = 0.f;
    __syncthreads();
    for (unsigned e=tid; e<ecnt; e+=1024){
      unsigned p = packed[estart+e];
      int s = p & 1023, d = (p>>10) & 1023;
      if (nmdi[s] != 0.f) atomicAdd(&aux[d], 1.f);
    }
    __syncthreads();
    {
      float nmv = nmdi[i];
      nmdi[i] = (nmv != 0.f) ? (1.f/sqrtf(1.f + aux[i])) : 0.f;
      #pragma unroll
      for (int f=0;f<8;f++) aT[f*1024+i] = 0.f;
    }
    __syncthreads();
    for (unsigned e=tid; e<ecnt; e+=1024){
      unsigned p = packed[estart+e];
      int s = p & 1023, d = (p>>10) & 1023;
      float co = nmdi[s]*nmdi[d];
      if (co != 0.f){
        #pragma unroll
        for (int f=0;f<8;f++) atomicAdd(&aT[f*1024+d], xT[f*1024+s]*co);
      }
    }
    __syncthreads();
    {
      float di = nmdi[i], d2 = di*di;
      float msk = (di != 0.f) ? 1.f : 0.f;
      float u[8];
      #pragma unroll
      for (int f=0;f<8;f++) u[f] = aT[f*1024+i] + d2*xT[f*1024+i];
      #pragma unroll
      for (int f=0;f<8;f++){
        float v = pB[f];
        #pragma unroll
        for (int fp=0;fp<8;fp++) v += pW[f*8+fp]*u[fp];
        v *= msk;
        xT[f*1024+i] = v > 0.f ? v : 0.f;
      }
    }
    __syncthreads();
    unsigned long long mykey;
    float myms;
    {
      float nrm = 0.f;
      #pragma unroll
      for (int f=0;f<8;f++) nrm += pT[f]*pT[f];
      float inv = 1.f/sqrtf(nrm);
      float s = 0.f;
      #pragma unroll
      for (int f=0;f<8;f++) s += xT[f*1024+i]*pT[f];
      s *= inv;
      s += 0.f;
      bool act = (nmdi[i] != 0.f);
      myms = act ? s : -INFINITY;
      aux[i] = myms;
      unsigned ub = __float_as_uint(myms);
      ub = (ub & 0x80000000u) ? ~ub : (ub | 0x80000000u);
      mykey = ((unsigned long long)ub << 32) | (unsigned)(~i);
      ((unsigned long long*)aT)[i] = mykey;
    }
    __syncthreads();
    int rank = 0;
    {
      const ulonglong2* kp = (const ulonglong2*)aT;
      for (int jb=0; jb<512; jb++){
        ulonglong2 kk = kp[jb];
        rank += (kk.x > mykey);
        rank += (kk.y > mykey);
      }
    }
    float kf = ceilf(0.8f*nactf);
    nactf = kf;
    const int kkeep = (int)kf;
    const bool keep = (rank < kkeep) && (nmdi[i] != 0.f);
    {
      float th = keep ? tanh_f(myms) : 0.f;
      #pragma unroll
      for (int f=0;f<8;f++) xT[f*1024+i] *= th;
      nmdi[i] = keep ? 1.f : 0.f;
    }
    __syncthreads();
    {
      float gi = pGB[0];
      #pragma unroll
      for (int f=0;f<8;f++) gi += xT[f*1024+i]*pGW[f];
      float gm = (nmdi[i] != 0.f) ? gi : -1e30f;
      float wm = gm;
      #pragma unroll
      for (int o=32;o>0;o>>=1) wm = fmaxf(wm, __shfl_xor(wm, o));
      const int wid = tid>>6;
      if ((tid&63)==0) red[wid] = wm;
      __syncthreads();
      float m = red[0];
      #pragma unroll
      for (int w=1;w<16;w++) m = fmaxf(m, red[w]);
      __syncthreads();
      float e = (nmdi[i] != 0.f) ? __expf(gi - m) : 0.f;
      float part[9];
      part[0] = e;
      #pragma unroll
      for (int f=0;f<8;f++) part[1+f] = e*xT[f*1024+i];
      #pragma unroll
      for (int qq=0;qq<9;qq++){
        float v = part[qq];
        #pragma unroll
        for (int o=32;o>0;o>>=1) v += __shfl_xor(v, o);
        if ((tid&63)==0) red[wid*9+qq] = v;
      }
      __syncthreads();
      if (tid < 64){
        float tot[9];
        #pragma unroll
        for (int qq=0;qq<9;qq++){
          float sv = 0.f;
          #pragma unroll
          for (int w=0;w<16;w++) sv += red[w*9+qq];
          tot[qq] = sv;
        }
        float sden = fmaxf(tot[0], 1e-12f);
        float o = pAttB[tid];
        #pragma unroll
        for (int f=0;f<8;f++) o += pAttW[tid*8+f]*(tot[1+f]/sden);
        outacc[tid] += o;
      }
      __syncthreads();
    }
  }
  if (tid < 64) gout[g2*64+tid] = outacc[tid];
}

// ================= K5: final combine =================
__global__ void combine_k(const float* __restrict__ rnnx, const float* __restrict__ gout,
                          const float* __restrict__ fcW, const float* __restrict__ fcb,
                          float* __restrict__ out)
{
  int b = threadIdx.x;
  if (b < B_){
    float s = fcb[0];
    #pragma unroll
    for (int q=0;q<8;q++) s += fcW[q]*rnnx[b*8+q];
    #pragma unroll
    for (int q=0;q<64;q++) s += fcW[8+q]*gout[b*64+q];
    out[b] = s;
  }
}

// ================= launch =================
extern "C" void kernel_launch(void* const* d_in, const int* in_sizes, int n_in,
                              void* d_out, int out_size, void* d_ws, size_t ws_size,
                              hipStream_t stream)
{
  const float* matrix    = (const float*)d_in[0];
  const int*   core_terms= (const int*)d_in[1];
  const int*   length    = (const int*)d_in[2];
  const float* x_graph   = (const float*)d_in[3];
  const int*   edge_src  = (const int*)d_in[4];
  const int*   edge_dst  = (const int*)d_in[5];
  const float* core_emb  = (const float*)d_in[7];
  const float* Wih0      = (const float*)d_in[8];
  const float* Whh0      = (const float*)d_in[9];
  const float* b0        = (const float*)d_in[10];
  const float* Wih1      = (const float*)d_in[11];
  const float* Whh1      = (const float*)d_in[12];
  const float* b1        = (const float*)d_in[13];
  const float* Wr        = (const float*)d_in[14];
  const float* br        = (const float*)d_in[15];
  const float* gcn_W     = (const float*)d_in[16];
  const float* gcn_b     = (const float*)d_in[17];
  const float* topk_w    = (const float*)d_in[18];
  const float* gate_W    = (const float*)d_in[19];
  const float* gate_b    = (const float*)d_in[20];
  const float* att_W     = (const float*)d_in[21];
  const float* att_b     = (const float*)d_in[22];
  const float* fc_W      = (const float*)d_in[23];
  const float* fc_b      = (const float*)d_in[24];
  float* out = (float*)d_out;

  char* ws = (char*)d_ws;
  float*    pre    = (float*)(ws + OFF_PRE);
  unsigned* packed = (unsigned*)(ws + OFF_PACK);
  unsigned* cnt    = (unsigned*)(ws + OFF_CNT);
  unsigned* starts = (unsigned*)(ws + OFF_START);
  unsigned* cursor = (unsigned*)(ws + OFF_CUR);
  float*    rnnx   = (float*)(ws + OFF_RNNX);
  float*    gout   = (float*)(ws + OFF_GOUT);

  hipMemsetAsync(cnt, 0, 512, stream);

  edge_count  <<<NE_/2048, 256, 0, stream>>>(edge_src, cnt);
  edge_scan   <<<1, 64, 0, stream>>>(cnt, starts, cursor);
  edge_scatter<<<NE_/2048, 256, 0, stream>>>(edge_src, edge_dst, cursor, packed);

  gemm_pre<<<dim3(2, M_/128), 256, 0, stream>>>(matrix, core_terms, core_emb, Wih0, b0, pre);
  lstm_k  <<<B_, 512, 0, stream>>>(pre, Whh0, Wih1, Whh1, b1, Wr, br, length, rnnx);

  constexpr int GNN_SMEM = 19321*4;
  hipFuncSetAttribute((const void*)gnn_k, hipFuncAttributeMaxDynamicSharedMemorySize, GNN_SMEM);
  gnn_k<<<NG_, 1024, GNN_SMEM, stream>>>(x_graph, packed, starts, cnt, gcn_W, gcn_b,
                                         topk_w, gate_W, gate_b, att_W, att_b, gout);

  combine_k<<<1, 128, 0, stream>>>(rnnx, gout, fc_W, fc_b, out);
}

// Round 7
// 1184.617 us; speedup vs baseline: 1.3474x; 1.3309x over previous
//
#include <hip/hip_runtime.h>
#include <math.h>

// ---------------- problem constants ----------------
constexpr int B_   = 128;
constexpr int T_   = 512;
constexpr int MFEAT= 256;   // matrix feature dim
constexpr int CEMB = 64;    // core emb dim
constexpr int INL  = 320;   // MFEAT + CEMB
constexpr int H_   = 64;    // lstm hidden
constexpr int G4   = 256;   // 4*H
constexpr int GN_  = 8;     // gnn feature
constexpr int NG_  = 128;   // graphs
constexpr int NPG_ = 1024;  // nodes per graph
constexpr int NE_  = 2*1024*1024;
constexpr int M_   = B_*T_; // 65536 rows for pre-GEMM

// ---------------- workspace layout (bytes) ----------------
constexpr size_t OFF_PRE   = 0;                           // M_*G4 f32 = 64MB (dead after lstm_k -> csr aliases here)
constexpr size_t OFF_PACK  = OFF_PRE + (size_t)M_*G4*4;   // NE_ u32 = 8MB
constexpr size_t OFF_CNT   = OFF_PACK + (size_t)NE_*4;    // 128 u32
constexpr size_t OFF_START = OFF_CNT + 512;               // 128 u32
constexpr size_t OFF_CUR   = OFF_START + 512;             // 128 u32
constexpr size_t OFF_RNNX  = OFF_CUR + 512;               // 128*8 f32
constexpr size_t OFF_GOUT  = OFF_RNNX + 4096;             // 128*64 f32

__device__ __forceinline__ float sigf(float x){ return 1.f/(1.f+__expf(-x)); }
__device__ __forceinline__ float tanh_f(float x){
  float xc = fminf(fmaxf(x, -15.f), 15.f);
  float t = __expf(2.f*xc);
  return (t-1.f)/(t+1.f);
}
__device__ __forceinline__ float rlane(float v, int k){
  return __int_as_float(__builtin_amdgcn_readlane(__float_as_int(v), k));
}

// ================= K1: pre-gate GEMM  pre[m][g] = x[m][:]@Wih0.T + b0 =================
__global__ void gemm_pre(const float* __restrict__ mat, const int* __restrict__ ct,
                         const float* __restrict__ emb, const float* __restrict__ Wih,
                         const float* __restrict__ b0, float* __restrict__ pre)
{
  __shared__ __align__(16) float As[8][128];
  __shared__ __align__(16) float Bs[8][128];
  const int tid = threadIdx.x;
  const int m0 = blockIdx.y*128, n0 = blockIdx.x*128;
  const int tr = tid>>4, tc = tid&15;
  const int ar = tid>>1, akq = (tid&1)*4;
  const int bn = tid&127, bkq = (tid>>7)*4;
  float acc[8][8] = {};
  for (int k0 = 0; k0 < INL; k0 += 8){
    const int ka = k0 + akq;
    const int row = m0 + ar;
    float4 av;
    if (ka < MFEAT) av = *(const float4*)(mat + (size_t)row*MFEAT + ka);
    else { int c = ct[row]; av = *(const float4*)(emb + (size_t)c*CEMB + (ka - MFEAT)); }
    As[akq+0][ar]=av.x; As[akq+1][ar]=av.y; As[akq+2][ar]=av.z; As[akq+3][ar]=av.w;
    float4 bv = *(const float4*)(Wih + (size_t)(n0+bn)*INL + k0 + bkq);
    Bs[bkq+0][bn]=bv.x; Bs[bkq+1][bn]=bv.y; Bs[bkq+2][bn]=bv.z; Bs[bkq+3][bn]=bv.w;
    __syncthreads();
    #pragma unroll
    for (int kk=0;kk<8;kk++){
      float a[8], bb[8];
      *(float4*)&a[0]  = *(const float4*)&As[kk][tr*8];
      *(float4*)&a[4]  = *(const float4*)&As[kk][tr*8+4];
      *(float4*)&bb[0] = *(const float4*)&Bs[kk][tc*8];
      *(float4*)&bb[4] = *(const float4*)&Bs[kk][tc*8+4];
      #pragma unroll
      for (int i=0;i<8;i++)
        #pragma unroll
        for (int jx=0;jx<8;jx++) acc[i][jx] += a[i]*bb[jx];
    }
    __syncthreads();
  }
  float bias[8];
  *(float4*)&bias[0] = *(const float4*)(b0 + n0 + tc*8);
  *(float4*)&bias[4] = *(const float4*)(b0 + n0 + tc*8 + 4);
  #pragma unroll
  for (int i=0;i<8;i++){
    float* dst = pre + (size_t)(m0 + tr*8 + i)*G4 + n0 + tc*8;
    float4 v0 = { acc[i][0]+bias[0], acc[i][1]+bias[1], acc[i][2]+bias[2], acc[i][3]+bias[3] };
    float4 v1 = { acc[i][4]+bias[4], acc[i][5]+bias[5], acc[i][6]+bias[6], acc[i][7]+bias[7] };
    *(float4*)dst = v0;
    *(float4*)(dst+4) = v1;
  }
}

// ================= K2: 16-wave split-K pipelined 2-layer LSTM =================
// wav 0-3 : L0 gates q=wav,  k in [0,32)   (carries pre term)
// wav 4-7 : L0 gates q=wav-4,k in [32,64)
// wav 8-11: L1 Wih1 part (vh0), k in [0,64)  (carries b1)
// wav 12-15: L1 Whh1 part (vh1), k in [0,64)
// h/c lane-distributed in registers, redundantly updated; broadcast via readlane.
__global__ __launch_bounds__(1024) void lstm_k(
    const float* __restrict__ pre, const float* __restrict__ Whh0,
    const float* __restrict__ Wih1, const float* __restrict__ Whh1,
    const float* __restrict__ b1, const float* __restrict__ Wr,
    const float* __restrict__ br, const int* __restrict__ length,
    float* __restrict__ rnnx)
{
  const int tid  = threadIdx.x;
  const int b    = blockIdx.x;
  const int wav  = tid >> 6;
  const int lane = tid & 63;
  const int q    = wav & 3;
  const int row  = q*64 + lane;

  __shared__ float pA[4][64], pB[4][64], pC[4][64], pD[4][64];
  __shared__ float lastv[H_];

  float w[64];
  if (wav < 4){
    #pragma unroll
    for (int k=0;k<32;k+=4) *(float4*)&w[k] = *(const float4*)(Whh0 + (size_t)row*H_ + k);
  } else if (wav < 8){
    #pragma unroll
    for (int k=0;k<32;k+=4) *(float4*)&w[k] = *(const float4*)(Whh0 + (size_t)row*H_ + 32 + k);
  } else if (wav < 12){
    #pragma unroll
    for (int k=0;k<64;k+=4) *(float4*)&w[k] = *(const float4*)(Wih1 + (size_t)row*H_ + k);
  } else {
    #pragma unroll
    for (int k=0;k<64;k+=4) *(float4*)&w[k] = *(const float4*)(Whh1 + (size_t)row*H_ + k);
  }
  const float bias1 = (wav>=8 && wav<12) ? b1[row] : 0.f;
  const int len = length[b];
  const float* preb = pre + (size_t)b*T_*G4;

  float vh0=0.f, vh1=0.f, c0=0.f, c1=0.f, vlast=0.f;
  float gcur = (wav<4) ? preb[row] : 0.f;
  float gnext = 0.f;

  for (int t=0; t<=T_; ++t){
    // ---- phase A: gate partials
    if (wav < 4){
      if (t < T_){
        gnext = (t+1<T_) ? preb[(size_t)(t+1)*G4 + row] : 0.f;
        float a0=gcur,a1=0.f,a2=0.f,a3=0.f;
        #pragma unroll
        for (int k=0;k<32;k+=4){
          a0 += rlane(vh0,k+0)*w[k+0];
          a1 += rlane(vh0,k+1)*w[k+1];
          a2 += rlane(vh0,k+2)*w[k+2];
          a3 += rlane(vh0,k+3)*w[k+3];
        }
        pA[q][lane] = (a0+a1)+(a2+a3);
      }
    } else if (wav < 8){
      if (t < T_){
        float a0=0.f,a1=0.f,a2=0.f,a3=0.f;
        #pragma unroll
        for (int k=0;k<32;k+=4){
          a0 += rlane(vh0,32+k+0)*w[k+0];
          a1 += rlane(vh0,32+k+1)*w[k+1];
          a2 += rlane(vh0,32+k+2)*w[k+2];
          a3 += rlane(vh0,32+k+3)*w[k+3];
        }
        pB[q][lane] = (a0+a1)+(a2+a3);
      }
    } else if (wav < 12){
      if (t >= 1){
        float a0=bias1,a1=0.f,a2=0.f,a3=0.f;
        #pragma unroll
        for (int k=0;k<64;k+=4){
          a0 += rlane(vh0,k+0)*w[k+0];
          a1 += rlane(vh0,k+1)*w[k+1];
          a2 += rlane(vh0,k+2)*w[k+2];
          a3 += rlane(vh0,k+3)*w[k+3];
        }
        pC[q][lane] = (a0+a1)+(a2+a3);
      }
    } else {
      if (t >= 1){
        float a0=0.f,a1=0.f,a2=0.f,a3=0.f;
        #pragma unroll
        for (int k=0;k<64;k+=4){
          a0 += rlane(vh1,k+0)*w[k+0];
          a1 += rlane(vh1,k+1)*w[k+1];
          a2 += rlane(vh1,k+2)*w[k+2];
          a3 += rlane(vh1,k+3)*w[k+3];
        }
        pD[q][lane] = (a0+a1)+(a2+a3);
      }
    }
    __syncthreads();
    // ---- phase B: redundant cell updates
    if (wav < 12){
      if (t < T_){
        float gi = sigf  (pA[0][lane]+pB[0][lane]);
        float gf = sigf  (pA[1][lane]+pB[1][lane]);
        float gg = tanh_f(pA[2][lane]+pB[2][lane]);
        float go = sigf  (pA[3][lane]+pB[3][lane]);
        c0  = gf*c0 + gi*gg;
        vh0 = go*tanh_f(c0);
      }
    } else {
      if (t >= 1){
        float gi = sigf  (pC[0][lane]+pD[0][lane]);
        float gf = sigf  (pC[1][lane]+pD[1][lane]);
        float gg = tanh_f(pC[2][lane]+pD[2][lane]);
        float go = sigf  (pC[3][lane]+pD[3][lane]);
        c1  = gf*c1 + gi*gg;
        vh1 = go*tanh_f(c1);
        if (t == len) vlast = vh1;
      }
    }
    __syncthreads();
    gcur = gnext;
  }
  if (wav == 12) lastv[lane] = vlast;
  __syncthreads();
  if (tid < GN_){
    float s = br[tid];
    #pragma unroll
    for (int k=0;k<H_;k++) s += lastv[k]*Wr[tid*H_+k];
    rnnx[b*GN_+tid] = s;
  }
}

// ================= K3: edge bucketing by graph =================
__global__ void edge_count(const int* __restrict__ src, unsigned* __restrict__ cnt)
{
  __shared__ unsigned lc[NG_];
  const int t = threadIdx.x;
  if (t < NG_) lc[t] = 0;
  __syncthreads();
  const int eb = blockIdx.x*2048;
  for (int i=t;i<2048;i+=256) atomicAdd(&lc[(unsigned)src[eb+i]>>10], 1u);
  __syncthreads();
  if (t < NG_ && lc[t]) atomicAdd(&cnt[t], lc[t]);
}

__global__ void edge_scan(const unsigned* __restrict__ cnt, unsigned* __restrict__ starts,
                          unsigned* __restrict__ cursor)
{
  if (threadIdx.x==0){
    unsigned s=0;
    for (int g2=0; g2<NG_; g2++){ starts[g2]=s; cursor[g2]=s; s+=cnt[g2]; }
  }
}

__global__ void edge_scatter(const int* __restrict__ src, const int* __restrict__ dst,
                             unsigned* __restrict__ cursor, unsigned* __restrict__ packed)
{
  __shared__ unsigned lc[NG_], base[NG_];
  const int t = threadIdx.x;
  if (t < NG_) lc[t] = 0;
  __syncthreads();
  const int eb = blockIdx.x*2048;
  for (int i=t;i<2048;i+=256) atomicAdd(&lc[(unsigned)src[eb+i]>>10], 1u);
  __syncthreads();
  if (t < NG_){
    unsigned c = lc[t];
    base[t] = c ? atomicAdd(&cursor[t], c) : 0u;
    lc[t] = 0;
  }
  __syncthreads();
  for (int i=t;i<2048;i+=256){
    unsigned s = (unsigned)src[eb+i], d = (unsigned)dst[eb+i];
    unsigned g2 = s>>10;
    unsigned off = atomicAdd(&lc[g2], 1u);
    packed[base[g2]+off] = (s & 1023u) | ((d & 1023u) << 10);
  }
}

// ================= K4: GNN — CSR gather + radix-select topk, 1 block/graph =================
__global__ __launch_bounds__(1024) void gnn_k(
  const float* __restrict__ xg, const unsigned* __restrict__ packed,
  const unsigned* __restrict__ starts, const unsigned* __restrict__ cnt,
  unsigned short* __restrict__ csr,
  const float* __restrict__ gcnW, const float* __restrict__ gcnB,
  const float* __restrict__ topkW, const float* __restrict__ gateW,
  const float* __restrict__ gateB, const float* __restrict__ attW,
  const float* __restrict__ attB, float* __restrict__ gout)
{
  __shared__ float xT[8][1024];
  __shared__ float nm[1024];
  __shared__ float di[1024];
  __shared__ unsigned rs[1025];
  __shared__ unsigned cur[1024];
  __shared__ unsigned hist[256];
  __shared__ unsigned warpsum[16];
  __shared__ unsigned selb[2];
  __shared__ float red[160];
  __shared__ float outacc[64];
  __shared__ float pAttW[512];
  __shared__ float pAttB[64];
  __shared__ float pW[64];
  __shared__ float pB8[8], pT8[8], pGW8[8], pGB1[1];

  const int tid = threadIdx.x;
  const int wav = tid>>6, lane = tid&63;
  const int g2  = blockIdx.x;
  const int i   = tid;
  const unsigned estart = starts[g2], ecnt = cnt[g2];

  {
    const float* xr = xg + (size_t)(g2*NPG_ + i)*GN_;
    float4 v0 = *(const float4*)(xr);
    float4 v1 = *(const float4*)(xr+4);
    xT[0][i]=v0.x; xT[1][i]=v0.y; xT[2][i]=v0.z; xT[3][i]=v0.w;
    xT[4][i]=v1.x; xT[5][i]=v1.y; xT[6][i]=v1.z; xT[7][i]=v1.w;
    nm[i] = 1.f;
  }
  if (tid < 512) pAttW[tid] = attW[tid];
  if (tid < 64) { pAttB[tid] = attB[tid]; outacc[tid] = 0.f; }

  // ---- CSR build (count -> scan -> scatter src as u16)
  cur[i] = 0;
  __syncthreads();
  for (unsigned e=tid; e<ecnt; e+=1024){
    unsigned p = packed[estart+e];
    atomicAdd(&cur[(p>>10)&1023u], 1u);
  }
  __syncthreads();
  unsigned myc = cur[i];
  unsigned v = myc;
  #pragma unroll
  for (int o=1;o<64;o<<=1){ unsigned u = __shfl_up(v,o); if (lane>=o) v += u; }
  if (lane==63) warpsum[wav] = v;
  __syncthreads();
  if (tid==0){
    unsigned s2=0;
    #pragma unroll
    for (int w2=0;w2<16;w2++){ unsigned t2=warpsum[w2]; warpsum[w2]=s2; s2+=t2; }
  }
  __syncthreads();
  unsigned myx = warpsum[wav] + v - myc;
  rs[i] = myx;
  if (tid==0) rs[1024] = ecnt;
  __syncthreads();
  cur[i] = myx;
  __syncthreads();
  for (unsigned e=tid; e<ecnt; e+=1024){
    unsigned p = packed[estart+e];
    unsigned d = (p>>10)&1023u;
    unsigned o = atomicAdd(&cur[d], 1u);
    csr[estart+o] = (unsigned short)(p & 1023u);
  }
  __syncthreads();

  const unsigned my_rs = rs[i], my_re = rs[i+1];
  float nactf = 1024.f;

  for (int it=0; it<4; ++it){
    if (tid < 64) pW[tid] = gcnW[it*64+tid];
    if (tid < 8) { pB8[tid] = gcnB[it*8+tid]; pT8[tid] = topkW[it*8+tid]; pGW8[tid] = gateW[tid]; }
    if (tid == 0) pGB1[0] = gateB[0];
    __syncthreads();
    // ---- degree (sum of src masks) + dinv
    float dsum = 0.f;
    for (unsigned e=my_rs; e<my_re; ++e) dsum += nm[csr[estart+e]];
    const bool act = nm[i] != 0.f;
    di[i] = act ? (1.f/sqrtf(dsum + 1.f)) : 0.f;
    __syncthreads();
    // ---- gather-aggregate raw x weighted by dinv[src]
    float a0=0,a1=0,a2=0,a3=0,a4=0,a5=0,a6=0,a7=0;
    for (unsigned e=my_rs; e<my_re; ++e){
      int s = csr[estart+e];
      float ws_ = di[s];
      a0 += xT[0][s]*ws_; a1 += xT[1][s]*ws_; a2 += xT[2][s]*ws_; a3 += xT[3][s]*ws_;
      a4 += xT[4][s]*ws_; a5 += xT[5][s]*ws_; a6 += xT[6][s]*ws_; a7 += xT[7][s]*ws_;
    }
    float dvi = di[i];
    float u[8] = {a0,a1,a2,a3,a4,a5,a6,a7};
    #pragma unroll
    for (int f=0;f<8;f++) u[f] = (u[f] + xT[f][i]*dvi) * dvi;
    float o_[8];
    const float msk = act ? 1.f : 0.f;
    #pragma unroll
    for (int f=0;f<8;f++){
      float y = pB8[f];
      #pragma unroll
      for (int fp=0;fp<8;fp++) y += pW[f*8+fp]*u[fp];
      o_[f] = fmaxf(y*msk, 0.f);
    }
    // ---- topk score + key
    float nrm = 0.f;
    #pragma unroll
    for (int f=0;f<8;f++) nrm += pT8[f]*pT8[f];
    float inv = 1.f/sqrtf(nrm);
    float sc = 0.f;
    #pragma unroll
    for (int f=0;f<8;f++) sc += o_[f]*pT8[f];
    sc *= inv;
    sc += 0.f;                      // canonicalize -0 -> +0
    float ms = act ? sc : -INFINITY;
    unsigned ub = __float_as_uint(ms);
    ub = (ub & 0x80000000u) ? ~ub : (ub | 0x80000000u);
    const unsigned long long key = ((unsigned long long)ub << 32) | (unsigned)(~i);
    int state = act ? 0 : -1;       // 0 cand, 1 keep, -1 drop
    float kf = ceilf(0.8f*nactf);
    nactf = kf;
    unsigned rem = (unsigned)kf;
    // ---- 8-pass radix select of k-th largest key
    for (int by=7; by>=0; --by){
      if (tid < 256) hist[tid] = 0u;
      __syncthreads();
      unsigned mb = (unsigned)((key >> (by*8)) & 255ull);
      if (state == 0) atomicAdd(&hist[mb], 1u);
      __syncthreads();
      if (wav == 0){
        uint4 h4 = *(const uint4*)&hist[lane*4];
        unsigned s3 = h4.w, s2_ = h4.z+s3, s1 = h4.y+s2_, s0 = h4.x+s1;
        unsigned suf = s0;
        #pragma unroll
        for (int o=1;o<64;o<<=1){ unsigned u2 = __shfl_down(suf,o); if (lane+o<64) suf += u2; }
        unsigned above = suf - s0;
        unsigned ge[4] = {above+s0, above+s1, above+s2_, above+s3};
        unsigned hv[4] = {h4.x, h4.y, h4.z, h4.w};
        #pragma unroll
        for (int j2=0;j2<4;j2++){
          unsigned gt = ge[j2] - hv[j2];
          if (gt < rem && rem <= ge[j2]){ selb[0] = (unsigned)(lane*4+j2); selb[1] = rem - gt; }
        }
      }
      __syncthreads();
      unsigned sb = selb[0];
      rem = selb[1];
      if (state == 0){ if (mb > sb) state = 1; else if (mb < sb) state = -1; }
    }
    const bool keep = state >= 0;
    // ---- apply pool + attpool (x kept in registers)
    float th = keep ? tanh_f(ms) : 0.f;
    float xf[8];
    #pragma unroll
    for (int f=0;f<8;f++) xf[f] = o_[f]*th;
    float gi = pGB1[0];
    #pragma unroll
    for (int f=0;f<8;f++) gi += xf[f]*pGW8[f];
    float gm = keep ? gi : -1e30f;
    float wm = gm;
    #pragma unroll
    for (int o=32;o>0;o>>=1) wm = fmaxf(wm, __shfl_xor(wm, o));
    if (lane==0) red[wav] = wm;
    __syncthreads();
    float m = red[0];
    #pragma unroll
    for (int w2=1;w2<16;w2++) m = fmaxf(m, red[w2]);
    __syncthreads();
    float ev = keep ? __expf(gi - m) : 0.f;
    float part[9];
    part[0] = ev;
    #pragma unroll
    for (int f=0;f<8;f++) part[1+f] = ev*xf[f];
    #pragma unroll
    for (int qq=0;qq<9;qq++){
      float vv = part[qq];
      #pragma unroll
      for (int o=32;o>0;o>>=1) vv += __shfl_xor(vv, o);
      if (lane==0) red[wav*9+qq] = vv;
    }
    // write next-iter state while reduce lands
    #pragma unroll
    for (int f=0;f<8;f++) xT[f][i] = xf[f];
    nm[i] = keep ? 1.f : 0.f;
    __syncthreads();
    if (tid < 64){
      float tot[9];
      #pragma unroll
      for (int qq=0;qq<9;qq++){
        float sv = 0.f;
        #pragma unroll
        for (int w2=0;w2<16;w2++) sv += red[w2*9+qq];
        tot[qq] = sv;
      }
      float sden = fmaxf(tot[0], 1e-12f);
      float oo = pAttB[tid];
      #pragma unroll
      for (int f=0;f<8;f++) oo += pAttW[tid*8+f]*(tot[1+f]/sden);
      outacc[tid] += oo;
    }
    __syncthreads();
  }
  if (tid < 64) gout[g2*64+tid] = outacc[tid];
}

// ================= K5: final combine =================
__global__ void combine_k(const float* __restrict__ rnnx, const float* __restrict__ gout,
                          const float* __restrict__ fcW, const float* __restrict__ fcb,
                          float* __restrict__ out)
{
  int b = threadIdx.x;
  if (b < B_){
    float s = fcb[0];
    #pragma unroll
    for (int q=0;q<8;q++) s += fcW[q]*rnnx[b*8+q];
    #pragma unroll
    for (int q=0;q<64;q++) s += fcW[8+q]*gout[b*64+q];
    out[b] = s;
  }
}

// ================= launch =================
extern "C" void kernel_launch(void* const* d_in, const int* in_sizes, int n_in,
                              void* d_out, int out_size, void* d_ws, size_t ws_size,
                              hipStream_t stream)
{
  const float* matrix    = (const float*)d_in[0];
  const int*   core_terms= (const int*)d_in[1];
  const int*   length    = (const int*)d_in[2];
  const float* x_graph   = (const float*)d_in[3];
  const int*   edge_src  = (const int*)d_in[4];
  const int*   edge_dst  = (const int*)d_in[5];
  const float* core_emb  = (const float*)d_in[7];
  const float* Wih0      = (const float*)d_in[8];
  const float* Whh0      = (const float*)d_in[9];
  const float* b0        = (const float*)d_in[10];
  const float* Wih1      = (const float*)d_in[11];
  const float* Whh1      = (const float*)d_in[12];
  const float* b1        = (const float*)d_in[13];
  const float* Wr        = (const float*)d_in[14];
  const float* br        = (const float*)d_in[15];
  const float* gcn_W     = (const float*)d_in[16];
  const float* gcn_b     = (const float*)d_in[17];
  const float* topk_w    = (const float*)d_in[18];
  const float* gate_W    = (const float*)d_in[19];
  const float* gate_b    = (const float*)d_in[20];
  const float* att_W     = (const float*)d_in[21];
  const float* att_b     = (const float*)d_in[22];
  const float* fc_W      = (const float*)d_in[23];
  const float* fc_b      = (const float*)d_in[24];
  float* out = (float*)d_out;

  char* ws = (char*)d_ws;
  float*    pre    = (float*)(ws + OFF_PRE);
  unsigned* packed = (unsigned*)(ws + OFF_PACK);
  unsigned* cnt    = (unsigned*)(ws + OFF_CNT);
  unsigned* starts = (unsigned*)(ws + OFF_START);
  unsigned* cursor = (unsigned*)(ws + OFF_CUR);
  float*    rnnx   = (float*)(ws + OFF_RNNX);
  float*    gout   = (float*)(ws + OFF_GOUT);
  // csr aliases the pre region: pre is dead once lstm_k (earlier in stream) completes
  unsigned short* csr = (unsigned short*)(ws + OFF_PRE);

  hipMemsetAsync(cnt, 0, 512, stream);

  edge_count  <<<NE_/2048, 256, 0, stream>>>(edge_src, cnt);
  edge_scan   <<<1, 64, 0, stream>>>(cnt, starts, cursor);
  edge_scatter<<<NE_/2048, 256, 0, stream>>>(edge_src, edge_dst, cursor, packed);

  gemm_pre<<<dim3(2, M_/128), 256, 0, stream>>>(matrix, core_terms, core_emb, Wih0, b0, pre);
  lstm_k  <<<B_, 1024, 0, stream>>>(pre, Whh0, Wih1, Whh1, b1, Wr, br, length, rnnx);

  gnn_k<<<NG_, 1024, 0, stream>>>(x_graph, packed, starts, cnt, csr, gcn_W, gcn_b,
                                  topk_w, gate_W, gate_b, att_W, att_b, gout);

  combine_k<<<1, 128, 0, stream>>>(rnnx, gout, fc_W, fc_b, out);
}

// Round 10
// 1029.061 us; speedup vs baseline: 1.5511x; 1.1512x over previous
//
#include <hip/hip_runtime.h>
#include <math.h>

// ---------------- problem constants ----------------
constexpr int B_   = 128;
constexpr int T_   = 512;
constexpr int MFEAT= 256;   // matrix feature dim
constexpr int CEMB = 64;    // core emb dim
constexpr int INL  = 320;   // MFEAT + CEMB
constexpr int H_   = 64;    // lstm hidden
constexpr int G4   = 256;   // 4*H
constexpr int GN_  = 8;     // gnn feature
constexpr int NG_  = 128;   // graphs
constexpr int NPG_ = 1024;  // nodes per graph
constexpr int NE_  = 2*1024*1024;
constexpr int M_   = B_*T_; // 65536 rows for pre-GEMM

// ---------------- workspace layout (bytes) ----------------
constexpr size_t OFF_PRE   = 0;                           // M_*G4 f32 = 64MB (dead after lstm_k -> csr aliases here)
constexpr size_t OFF_PACK  = OFF_PRE + (size_t)M_*G4*4;   // NE_ u32 = 8MB
constexpr size_t OFF_CNT   = OFF_PACK + (size_t)NE_*4;    // 128 u32
constexpr size_t OFF_START = OFF_CNT + 512;               // 128 u32
constexpr size_t OFF_CUR   = OFF_START + 512;             // 128 u32
constexpr size_t OFF_RNNX  = OFF_CUR + 512;               // 128*8 f32
constexpr size_t OFF_GOUT  = OFF_RNNX + 4096;             // 128*64 f32

__device__ __forceinline__ float sigf(float x){ return 1.f/(1.f+__expf(-x)); }
__device__ __forceinline__ float tanh_f(float x){
  float xc = fminf(fmaxf(x, -15.f), 15.f);
  float t = __expf(2.f*xc);
  return (t-1.f)/(t+1.f);
}
__device__ __forceinline__ float rlane(float v, int k){
  return __int_as_float(__builtin_amdgcn_readlane(__float_as_int(v), k));
}

// ================= K1: pre-gate GEMM  pre[m][g] = x[m][:]@Wih0.T + b0 =================
__global__ void gemm_pre(const float* __restrict__ mat, const int* __restrict__ ct,
                         const float* __restrict__ emb, const float* __restrict__ Wih,
                         const float* __restrict__ b0, float* __restrict__ pre)
{
  __shared__ __align__(16) float As[8][128];
  __shared__ __align__(16) float Bs[8][128];
  const int tid = threadIdx.x;
  const int m0 = blockIdx.y*128, n0 = blockIdx.x*128;
  const int tr = tid>>4, tc = tid&15;
  const int ar = tid>>1, akq = (tid&1)*4;
  const int bn = tid&127, bkq = (tid>>7)*4;
  float acc[8][8] = {};
  for (int k0 = 0; k0 < INL; k0 += 8){
    const int ka = k0 + akq;
    const int row = m0 + ar;
    float4 av;
    if (ka < MFEAT) av = *(const float4*)(mat + (size_t)row*MFEAT + ka);
    else { int c = ct[row]; av = *(const float4*)(emb + (size_t)c*CEMB + (ka - MFEAT)); }
    As[akq+0][ar]=av.x; As[akq+1][ar]=av.y; As[akq+2][ar]=av.z; As[akq+3][ar]=av.w;
    float4 bv = *(const float4*)(Wih + (size_t)(n0+bn)*INL + k0 + bkq);
    Bs[bkq+0][bn]=bv.x; Bs[bkq+1][bn]=bv.y; Bs[bkq+2][bn]=bv.z; Bs[bkq+3][bn]=bv.w;
    __syncthreads();
    #pragma unroll
    for (int kk=0;kk<8;kk++){
      float a[8], bb[8];
      *(float4*)&a[0]  = *(const float4*)&As[kk][tr*8];
      *(float4*)&a[4]  = *(const float4*)&As[kk][tr*8+4];
      *(float4*)&bb[0] = *(const float4*)&Bs[kk][tc*8];
      *(float4*)&bb[4] = *(const float4*)&Bs[kk][tc*8+4];
      #pragma unroll
      for (int i=0;i<8;i++)
        #pragma unroll
        for (int jx=0;jx<8;jx++) acc[i][jx] += a[i]*bb[jx];
    }
    __syncthreads();
  }
  float bias[8];
  *(float4*)&bias[0] = *(const float4*)(b0 + n0 + tc*8);
  *(float4*)&bias[4] = *(const float4*)(b0 + n0 + tc*8 + 4);
  #pragma unroll
  for (int i=0;i<8;i++){
    float* dst = pre + (size_t)(m0 + tr*8 + i)*G4 + n0 + tc*8;
    float4 v0 = { acc[i][0]+bias[0], acc[i][1]+bias[1], acc[i][2]+bias[2], acc[i][3]+bias[3] };
    float4 v1 = { acc[i][4]+bias[4], acc[i][5]+bias[5], acc[i][6]+bias[6], acc[i][7]+bias[7] };
    *(float4*)dst = v0;
    *(float4*)(dst+4) = v1;
  }
}

// ================= K2: 12-wave balanced LSTM, LDS-chunked pre, 1 barrier/step =================
// grp0 (waves 0-3):  L0 gate q = Whh0@h0 + pre  (pre-activated into gs0)
// grp1 (waves 4-7):  L1 partial pC = Wih1@h0 + b1   (for gates at t-1)
// grp2 (waves 8-11): L1 partial pD = Whh1@h1        (for gates at t-1)
// h0: regs in grp0+grp1; h1: regs in grp2. Gate/partial LDS parity double-buffered.
// pre staged HBM->LDS in 64-step chunks: vmcnt drain at barriers hits once per 64 steps.
__global__ __launch_bounds__(768) void lstm_k(
    const float* __restrict__ pre, const float* __restrict__ Whh0,
    const float* __restrict__ Wih1, const float* __restrict__ Whh1,
    const float* __restrict__ b1, const float* __restrict__ Wr,
    const float* __restrict__ br, const int* __restrict__ length,
    float* __restrict__ rnnx)
{
  extern __shared__ __align__(16) char smem[];
  float* preC = (float*)smem;            // [2][64][256] = 128KB
  float* gs0  = preC + 2*64*256;         // [2][256] pre-activated L0 gates
  float* pC   = gs0 + 512;               // [2][256] L1 ih partial (incl b1)
  float* pD   = pC + 512;                // [2][256] L1 hh partial
  float* lastv= pD + 512;                // [64]

  const int tid  = threadIdx.x;
  const int b    = blockIdx.x;
  const int wav  = tid >> 6;
  const int lane = tid & 63;
  const int q    = wav & 3;
  const int row  = q*64 + lane;
  const int grp  = wav >> 2;             // 0,1,2

  float w[64];
  const float* wsrc = (grp==0) ? Whh0 : (grp==1) ? Wih1 : Whh1;
  #pragma unroll
  for (int k=0;k<64;k+=4) *(float4*)&w[k] = *(const float4*)(wsrc + (size_t)row*H_ + k);
  const float bias1 = (grp==1) ? b1[row] : 0.f;
  const int len = length[b];
  const float* preb = pre + (size_t)b*T_*G4;

  // stage chunk 0 (t = 0..63)
  for (int idx = tid; idx < 4096; idx += 768)
    *(float4*)(preC + idx*4) = *(const float4*)(preb + idx*4);
  __syncthreads();

  float vh0=0.f, vh1=0.f, c0=0.f, c1=0.f, vlast=0.f;

  for (int t=0; t<=T_; ++t){
    const int p = t & 1;
    // ---- stage next pre chunk (double-buffered; once per 64 steps)
    if ((t & 63) == 0 && t < 448){
      const int cn = (t>>6) + 1;
      float* dstb = preC + (cn & 1)*64*256;
      const float* srcb = preb + (size_t)cn*64*256;
      for (int idx = tid; idx < 4096; idx += 768)
        *(float4*)(dstb + idx*4) = *(const float4*)(srcb + idx*4);
    }
    // ---- phase A: matvec partials (readlane broadcast of reg-held h)
    if (grp == 0){
      if (t < T_){
        float gpre = preC[((t>>6)&1)*16384 + (t&63)*256 + row];
        float a0=0.f,a1=0.f,a2=0.f,a3=0.f;
        #pragma unroll
        for (int k=0;k<64;k+=4){
          a0 += rlane(vh0,k+0)*w[k+0];
          a1 += rlane(vh0,k+1)*w[k+1];
          a2 += rlane(vh0,k+2)*w[k+2];
          a3 += rlane(vh0,k+3)*w[k+3];
        }
        float g = gpre + ((a0+a1)+(a2+a3));
        gs0[p*256+row] = (q==2) ? tanh_f(g) : sigf(g);
      }
    } else if (grp == 1){
      if (t >= 1){
        float a0=bias1,a1=0.f,a2=0.f,a3=0.f;
        #pragma unroll
        for (int k=0;k<64;k+=4){
          a0 += rlane(vh0,k+0)*w[k+0];
          a1 += rlane(vh0,k+1)*w[k+1];
          a2 += rlane(vh0,k+2)*w[k+2];
          a3 += rlane(vh0,k+3)*w[k+3];
        }
        pC[p*256+row] = (a0+a1)+(a2+a3);
      }
    } else {
      if (t >= 1){
        float a0=0.f,a1=0.f,a2=0.f,a3=0.f;
        #pragma unroll
        for (int k=0;k<64;k+=4){
          a0 += rlane(vh1,k+0)*w[k+0];
          a1 += rlane(vh1,k+1)*w[k+1];
          a2 += rlane(vh1,k+2)*w[k+2];
          a3 += rlane(vh1,k+3)*w[k+3];
        }
        pD[p*256+row] = (a0+a1)+(a2+a3);
      }
    }
    __syncthreads();
    // ---- phase B: cell updates (parity buffer => no 2nd barrier)
    if (grp < 2){
      if (t < T_){
        float gi = gs0[p*256+lane];
        float gf = gs0[p*256+64+lane];
        float gg = gs0[p*256+128+lane];
        float go = gs0[p*256+192+lane];
        c0  = gf*c0 + gi*gg;
        vh0 = go*tanh_f(c0);
      }
    } else {
      if (t >= 1){
        float xi = pC[p*256+lane]     + pD[p*256+lane];
        float xf = pC[p*256+64+lane]  + pD[p*256+64+lane];
        float xg = pC[p*256+128+lane] + pD[p*256+128+lane];
        float xo = pC[p*256+192+lane] + pD[p*256+192+lane];
        float gi=sigf(xi), gf=sigf(xf), gg=tanh_f(xg), go=sigf(xo);
        c1  = gf*c1 + gi*gg;
        vh1 = go*tanh_f(c1);
        if (t == len) vlast = vh1;   // vh1 == h1(len-1)
      }
    }
  }
  if (wav == 8) lastv[lane] = vlast;
  __syncthreads();
  if (tid < GN_){
    float s = br[tid];
    #pragma unroll
    for (int k=0;k<H_;k++) s += lastv[k]*Wr[tid*H_+k];
    rnnx[b*GN_+tid] = s;
  }
}

// ================= K3: edge bucketing by graph =================
__global__ void edge_count(const int* __restrict__ src, unsigned* __restrict__ cnt)
{
  __shared__ unsigned lc[NG_];
  const int t = threadIdx.x;
  if (t < NG_) lc[t] = 0;
  __syncthreads();
  const int eb = blockIdx.x*2048;
  for (int i=t;i<2048;i+=256) atomicAdd(&lc[(unsigned)src[eb+i]>>10], 1u);
  __syncthreads();
  if (t < NG_ && lc[t]) atomicAdd(&cnt[t], lc[t]);
}

__global__ void edge_scan(const unsigned* __restrict__ cnt, unsigned* __restrict__ starts,
                          unsigned* __restrict__ cursor)
{
  if (threadIdx.x==0){
    unsigned s=0;
    for (int g2=0; g2<NG_; g2++){ starts[g2]=s; cursor[g2]=s; s+=cnt[g2]; }
  }
}

__global__ void edge_scatter(const int* __restrict__ src, const int* __restrict__ dst,
                             unsigned* __restrict__ cursor, unsigned* __restrict__ packed)
{
  __shared__ unsigned lc[NG_], base[NG_];
  const int t = threadIdx.x;
  if (t < NG_) lc[t] = 0;
  __syncthreads();
  const int eb = blockIdx.x*2048;
  for (int i=t;i<2048;i+=256) atomicAdd(&lc[(unsigned)src[eb+i]>>10], 1u);
  __syncthreads();
  if (t < NG_){
    unsigned c = lc[t];
    base[t] = c ? atomicAdd(&cursor[t], c) : 0u;
    lc[t] = 0;
  }
  __syncthreads();
  for (int i=t;i<2048;i+=256){
    unsigned s = (unsigned)src[eb+i], d = (unsigned)dst[eb+i];
    unsigned g2 = s>>10;
    unsigned off = atomicAdd(&lc[g2], 1u);
    packed[base[g2]+off] = (s & 1023u) | ((d & 1023u) << 10);
  }
}

// ================= K4: GNN — CSR gather + radix-select topk, 1 block/graph =================
__global__ __launch_bounds__(1024) void gnn_k(
  const float* __restrict__ xg, const unsigned* __restrict__ packed,
  const unsigned* __restrict__ starts, const unsigned* __restrict__ cnt,
  unsigned short* __restrict__ csr,
  const float* __restrict__ gcnW, const float* __restrict__ gcnB,
  const float* __restrict__ topkW, const float* __restrict__ gateW,
  const float* __restrict__ gateB, const float* __restrict__ attW,
  const float* __restrict__ attB, float* __restrict__ gout)
{
  __shared__ float xT[8][1024];
  __shared__ float nm[1024];
  __shared__ float di[1024];
  __shared__ unsigned rs[1025];
  __shared__ unsigned cur[1024];
  __shared__ unsigned hist[256];
  __shared__ unsigned warpsum[16];
  __shared__ unsigned selb[2];
  __shared__ float red[160];
  __shared__ float outacc[64];
  __shared__ float pAttW[512];
  __shared__ float pAttB[64];
  __shared__ float pW[64];
  __shared__ float pB8[8], pT8[8], pGW8[8], pGB1[1];

  const int tid = threadIdx.x;
  const int wav = tid>>6, lane = tid&63;
  const int g2  = blockIdx.x;
  const int i   = tid;
  const unsigned estart = starts[g2], ecnt = cnt[g2];

  {
    const float* xr = xg + (size_t)(g2*NPG_ + i)*GN_;
    float4 v0 = *(const float4*)(xr);
    float4 v1 = *(const float4*)(xr+4);
    xT[0][i]=v0.x; xT[1][i]=v0.y; xT[2][i]=v0.z; xT[3][i]=v0.w;
    xT[4][i]=v1.x; xT[5][i]=v1.y; xT[6][i]=v1.z; xT[7][i]=v1.w;
    nm[i] = 1.f;
  }
  if (tid < 512) pAttW[tid] = attW[tid];
  if (tid < 64) { pAttB[tid] = attB[tid]; outacc[tid] = 0.f; }

  // ---- CSR build (count -> scan -> scatter src as u16)
  cur[i] = 0;
  __syncthreads();
  for (unsigned e=tid; e<ecnt; e+=1024){
    unsigned p = packed[estart+e];
    atomicAdd(&cur[(p>>10)&1023u], 1u);
  }
  __syncthreads();
  unsigned myc = cur[i];
  unsigned v = myc;
  #pragma unroll
  for (int o=1;o<64;o<<=1){ unsigned u = __shfl_up(v,o); if (lane>=o) v += u; }
  if (lane==63) warpsum[wav] = v;
  __syncthreads();
  if (tid==0){
    unsigned s2=0;
    #pragma unroll
    for (int w2=0;w2<16;w2++){ unsigned t2=warpsum[w2]; warpsum[w2]=s2; s2+=t2; }
  }
  __syncthreads();
  unsigned myx = warpsum[wav] + v - myc;
  rs[i] = myx;
  if (tid==0) rs[1024] = ecnt;
  __syncthreads();
  cur[i] = myx;
  __syncthreads();
  for (unsigned e=tid; e<ecnt; e+=1024){
    unsigned p = packed[estart+e];
    unsigned d = (p>>10)&1023u;
    unsigned o = atomicAdd(&cur[d], 1u);
    csr[estart+o] = (unsigned short)(p & 1023u);
  }
  __syncthreads();

  const unsigned my_rs = rs[i], my_re = rs[i+1];
  float nactf = 1024.f;

  for (int it=0; it<4; ++it){
    if (tid < 64) pW[tid] = gcnW[it*64+tid];
    if (tid < 8) { pB8[tid] = gcnB[it*8+tid]; pT8[tid] = topkW[it*8+tid]; pGW8[tid] = gateW[tid]; }
    if (tid == 0) pGB1[0] = gateB[0];
    __syncthreads();
    // ---- degree (sum of src masks) + dinv
    float dsum = 0.f;
    for (unsigned e=my_rs; e<my_re; ++e) dsum += nm[csr[estart+e]];
    const bool act = nm[i] != 0.f;
    di[i] = act ? (1.f/sqrtf(dsum + 1.f)) : 0.f;
    __syncthreads();
    // ---- gather-aggregate raw x weighted by dinv[src]
    float a0=0,a1=0,a2=0,a3=0,a4=0,a5=0,a6=0,a7=0;
    for (unsigned e=my_rs; e<my_re; ++e){
      int s = csr[estart+e];
      float ws_ = di[s];
      a0 += xT[0][s]*ws_; a1 += xT[1][s]*ws_; a2 += xT[2][s]*ws_; a3 += xT[3][s]*ws_;
      a4 += xT[4][s]*ws_; a5 += xT[5][s]*ws_; a6 += xT[6][s]*ws_; a7 += xT[7][s]*ws_;
    }
    float dvi = di[i];
    float u[8] = {a0,a1,a2,a3,a4,a5,a6,a7};
    #pragma unroll
    for (int f=0;f<8;f++) u[f] = (u[f] + xT[f][i]*dvi) * dvi;
    float o_[8];
    const float msk = act ? 1.f : 0.f;
    #pragma unroll
    for (int f=0;f<8;f++){
      float y = pB8[f];
      #pragma unroll
      for (int fp=0;fp<8;fp++) y += pW[f*8+fp]*u[fp];
      o_[f] = fmaxf(y*msk, 0.f);
    }
    // ---- topk score + key
    float nrm = 0.f;
    #pragma unroll
    for (int f=0;f<8;f++) nrm += pT8[f]*pT8[f];
    float inv = 1.f/sqrtf(nrm);
    float sc = 0.f;
    #pragma unroll
    for (int f=0;f<8;f++) sc += o_[f]*pT8[f];
    sc *= inv;
    sc += 0.f;                      // canonicalize -0 -> +0
    float ms = act ? sc : -INFINITY;
    unsigned ub = __float_as_uint(ms);
    ub = (ub & 0x80000000u) ? ~ub : (ub | 0x80000000u);
    const unsigned long long key = ((unsigned long long)ub << 32) | (unsigned)(~i);
    int state = act ? 0 : -1;       // 0 cand, 1 keep, -1 drop
    float kf = ceilf(0.8f*nactf);
    nactf = kf;
    unsigned rem = (unsigned)kf;
    // ---- 8-pass radix select of k-th largest key
    for (int by=7; by>=0; --by){
      if (tid < 256) hist[tid] = 0u;
      __syncthreads();
      unsigned mb = (unsigned)((key >> (by*8)) & 255ull);
      if (state == 0) atomicAdd(&hist[mb], 1u);
      __syncthreads();
      if (wav == 0){
        uint4 h4 = *(const uint4*)&hist[lane*4];
        unsigned s3 = h4.w, s2_ = h4.z+s3, s1 = h4.y+s2_, s0 = h4.x+s1;
        unsigned suf = s0;
        #pragma unroll
        for (int o=1;o<64;o<<=1){ unsigned u2 = __shfl_down(suf,o); if (lane+o<64) suf += u2; }
        unsigned above = suf - s0;
        unsigned ge[4] = {above+s0, above+s1, above+s2_, above+s3};
        unsigned hv[4] = {h4.x, h4.y, h4.z, h4.w};
        #pragma unroll
        for (int j2=0;j2<4;j2++){
          unsigned gt = ge[j2] - hv[j2];
          if (gt < rem && rem <= ge[j2]){ selb[0] = (unsigned)(lane*4+j2); selb[1] = rem - gt; }
        }
      }
      __syncthreads();
      unsigned sb = selb[0];
      rem = selb[1];
      if (state == 0){ if (mb > sb) state = 1; else if (mb < sb) state = -1; }
    }
    const bool keep = state >= 0;
    // ---- apply pool + attpool (x kept in registers)
    float th = keep ? tanh_f(ms) : 0.f;
    float xf[8];
    #pragma unroll
    for (int f=0;f<8;f++) xf[f] = o_[f]*th;
    float gi = pGB1[0];
    #pragma unroll
    for (int f=0;f<8;f++) gi += xf[f]*pGW8[f];
    float gm = keep ? gi : -1e30f;
    float wm = gm;
    #pragma unroll
    for (int o=32;o>0;o>>=1) wm = fmaxf(wm, __shfl_xor(wm, o));
    if (lane==0) red[wav] = wm;
    __syncthreads();
    float m = red[0];
    #pragma unroll
    for (int w2=1;w2<16;w2++) m = fmaxf(m, red[w2]);
    __syncthreads();
    float ev = keep ? __expf(gi - m) : 0.f;
    float part[9];
    part[0] = ev;
    #pragma unroll
    for (int f=0;f<8;f++) part[1+f] = ev*xf[f];
    #pragma unroll
    for (int qq=0;qq<9;qq++){
      float vv = part[qq];
      #pragma unroll
      for (int o=32;o>0;o>>=1) vv += __shfl_xor(vv, o);
      if (lane==0) red[wav*9+qq] = vv;
    }
    // write next-iter state while reduce lands
    #pragma unroll
    for (int f=0;f<8;f++) xT[f][i] = xf[f];
    nm[i] = keep ? 1.f : 0.f;
    __syncthreads();
    if (tid < 64){
      float tot[9];
      #pragma unroll
      for (int qq=0;qq<9;qq++){
        float sv = 0.f;
        #pragma unroll
        for (int w2=0;w2<16;w2++) sv += red[w2*9+qq];
        tot[qq] = sv;
      }
      float sden = fmaxf(tot[0], 1e-12f);
      float oo = pAttB[tid];
      #pragma unroll
      for (int f=0;f<8;f++) oo += pAttW[tid*8+f]*(tot[1+f]/sden);
      outacc[tid] += oo;
    }
    __syncthreads();
  }
  if (tid < 64) gout[g2*64+tid] = outacc[tid];
}

// ================= K5: final combine =================
__global__ void combine_k(const float* __restrict__ rnnx, const float* __restrict__ gout,
                          const float* __restrict__ fcW, const float* __restrict__ fcb,
                          float* __restrict__ out)
{
  int b = threadIdx.x;
  if (b < B_){
    float s = fcb[0];
    #pragma unroll
    for (int q=0;q<8;q++) s += fcW[q]*rnnx[b*8+q];
    #pragma unroll
    for (int q=0;q<64;q++) s += fcW[8+q]*gout[b*64+q];
    out[b] = s;
  }
}

// ================= launch =================
extern "C" void kernel_launch(void* const* d_in, const int* in_sizes, int n_in,
                              void* d_out, int out_size, void* d_ws, size_t ws_size,
                              hipStream_t stream)
{
  const float* matrix    = (const float*)d_in[0];
  const int*   core_terms= (const int*)d_in[1];
  const int*   length    = (const int*)d_in[2];
  const float* x_graph   = (const float*)d_in[3];
  const int*   edge_src  = (const int*)d_in[4];
  const int*   edge_dst  = (const int*)d_in[5];
  const float* core_emb  = (const float*)d_in[7];
  const float* Wih0      = (const float*)d_in[8];
  const float* Whh0      = (const float*)d_in[9];
  const float* b0        = (const float*)d_in[10];
  const float* Wih1      = (const float*)d_in[11];
  const float* Whh1      = (const float*)d_in[12];
  const float* b1        = (const float*)d_in[13];
  const float* Wr        = (const float*)d_in[14];
  const float* br        = (const float*)d_in[15];
  const float* gcn_W     = (const float*)d_in[16];
  const float* gcn_b     = (const float*)d_in[17];
  const float* topk_w    = (const float*)d_in[18];
  const float* gate_W    = (const float*)d_in[19];
  const float* gate_b    = (const float*)d_in[20];
  const float* att_W     = (const float*)d_in[21];
  const float* att_b     = (const float*)d_in[22];
  const float* fc_W      = (const float*)d_in[23];
  const float* fc_b      = (const float*)d_in[24];
  float* out = (float*)d_out;

  char* ws = (char*)d_ws;
  float*    pre    = (float*)(ws + OFF_PRE);
  unsigned* packed = (unsigned*)(ws + OFF_PACK);
  unsigned* cnt    = (unsigned*)(ws + OFF_CNT);
  unsigned* starts = (unsigned*)(ws + OFF_START);
  unsigned* cursor = (unsigned*)(ws + OFF_CUR);
  float*    rnnx   = (float*)(ws + OFF_RNNX);
  float*    gout   = (float*)(ws + OFF_GOUT);
  // csr aliases the pre region: pre is dead once lstm_k (earlier in stream) completes
  unsigned short* csr = (unsigned short*)(ws + OFF_PRE);

  hipMemsetAsync(cnt, 0, 512, stream);

  edge_count  <<<NE_/2048, 256, 0, stream>>>(edge_src, cnt);
  edge_scan   <<<1, 64, 0, stream>>>(cnt, starts, cursor);
  edge_scatter<<<NE_/2048, 256, 0, stream>>>(edge_src, edge_dst, cursor, packed);

  gemm_pre<<<dim3(2, M_/128), 256, 0, stream>>>(matrix, core_terms, core_emb, Wih0, b0, pre);

  // lstm: 128KB pre-chunk double buffer + 6KB gate buffers of dynamic LDS
  constexpr int LSTM_SMEM = (2*64*256 + 3*512 + 64) * 4;   // 137472 B
  hipFuncSetAttribute((const void*)lstm_k, hipFuncAttributeMaxDynamicSharedMemorySize, LSTM_SMEM);
  lstm_k<<<B_, 768, LSTM_SMEM, stream>>>(pre, Whh0, Wih1, Whh1, b1, Wr, br, length, rnnx);

  gnn_k<<<NG_, 1024, 0, stream>>>(x_graph, packed, starts, cnt, csr, gcn_W, gcn_b,
                                  topk_w, gate_W, gate_b, att_W, att_b, gout);

  combine_k<<<1, 128, 0, stream>>>(rnnx, gout, fc_W, fc_b, out);
}